// Round 3
// baseline (362.713 us; speedup 1.0000x reference)
//
#include <hip/hip_runtime.h>

// Problem: B=256, N=131072, F=16. Two-pass causal FIR with masking:
//   v[i] = (i>=16) ? x[i] + sum_{j<16} h[j]*x[i-1-j] : 0
//   y[i] = (i>=16) ? v[i] + sum_{j<16} h[15-j]*v[i-1-j] : 0
// For i >= 32: y = 33-tap conv with g = conv([1,h], [1,reverse(h)]).
//
// R2 -> R3: R2 was still latency-bound (26% HBM, 22% VALU): stores were
// 64B-per-lane strided (since R1) and 48 ds_read_b32/thread exposed lgkm
// waits. Now lane t owns ONE float4 of output -> every global load/store
// is perfectly lane-contiguous (1KB/instr). Window = 10 aligned dwordx4
// loads (chunks cid-9..cid); adjacent instructions re-hit L1 (~90%).
// No LDS, no barrier, 10 independent loads in flight.

#define NROW 131072

__global__ void compute_g_kernel(const float* __restrict__ h, float* __restrict__ g) {
    int m = threadIdx.x;
    if (m < 33) {
        float s = 0.f;
        for (int a = 0; a <= 16; ++a) {
            int b = m - a;
            if (b < 0 || b > 16) continue;
            float ka = (a == 0) ? 1.f : h[a - 1];
            float kb = (b == 0) ? 1.f : h[16 - b];
            s += ka * kb;
        }
        g[m] = s;
    }
}

// grid: 256 rows x 128 blocks/row = 32768 blocks, 256 threads.
// thread -> float4-chunk cid in [0, 32768) of its row; outputs [4cid, 4cid+4).
__global__ __launch_bounds__(256) void fir2_kernel(const float* __restrict__ x,
                                                   const float* __restrict__ h,
                                                   const float* __restrict__ g,
                                                   float* __restrict__ y) {
    const int bid = blockIdx.x;
    const int row = bid >> 7;
    const int cid = ((bid & 127) << 8) + (int)threadIdx.x;
    const int o0 = cid << 2;
    const float* __restrict__ xr = x + (size_t)row * NROW;
    float* __restrict__ yr = y + (size_t)row * NROW;

    float gg[33];
#pragma unroll
    for (int m = 0; m < 33; ++m) gg[m] = g[m];     // uniform -> s_load

    // w[k] = x[o0 - 36 + k], k = 0..39  (chunks cid-9 .. cid)
    float w[40];

    if (bid & 127) {
        // ---- fast path (wave-uniform): no row boundary in window ----
#pragma unroll
        for (int k = 0; k < 10; ++k) {
            float4 v = *(const float4*)(xr + (o0 - 36 + 4 * k));
            w[4 * k + 0] = v.x; w[4 * k + 1] = v.y;
            w[4 * k + 2] = v.z; w[4 * k + 3] = v.w;
        }
        float o[4];
#pragma unroll
        for (int c = 0; c < 4; ++c) {
            float s = 0.f;
#pragma unroll
            for (int m = 0; m < 33; ++m) s += gg[m] * w[36 + c - m];
            o[c] = s;
        }
        *(float4*)(yr + o0) = make_float4(o[0], o[1], o[2], o[3]);
    } else {
        // ---- boundary path: first block of each row (cid 0..255) ----
#pragma unroll
        for (int k = 0; k < 10; ++k) {
            const int ck = cid - 9 + k;
            float4 v;
            if (ck >= 0) v = *(const float4*)(xr + 4 * ck);
            else         v = make_float4(0.f, 0.f, 0.f, 0.f);
            w[4 * k + 0] = v.x; w[4 * k + 1] = v.y;
            w[4 * k + 2] = v.z; w[4 * k + 3] = v.w;
        }
        float o[4];
        if (cid >= 8) {
            // generic: window fully valid (x index >= 4cid-32 >= 0)
#pragma unroll
            for (int c = 0; c < 4; ++c) {
                float s = 0.f;
#pragma unroll
                for (int m = 0; m < 33; ++m) s += gg[m] * w[36 + c - m];
                o[c] = s;
            }
        } else if (cid < 4) {
            o[0] = o[1] = o[2] = o[3] = 0.f;        // outputs 0..15
        } else {
            // cid in [4,8): outputs o0..o0+3 in [16,32): explicit two-stage.
            // x[q] = w[q - o0 + 36] for q in [o0-36, o0+4).
            float hh[16];
            for (int j = 0; j < 16; ++j) hh[j] = h[j];
            const int umax = o0 + 3 - 16;            // v[16..16+umax] needed
            float vv[16];                            // vv[u] = v[16+u]
            for (int u = 0; u <= umax; ++u) {
                const int p = 16 + u;
                float s = w[p - o0 + 36];            // x[p]
                for (int j = 0; j < 16; ++j)
                    s += hh[j] * w[p - 1 - j - o0 + 36];   // x[p-1-j], >= x[0]
                vv[u] = s;
            }
            for (int c = 0; c < 4; ++c) {
                const int i = o0 + c;
                float s = vv[i - 16];
                for (int j = 0; j < 16; ++j) {
                    const int idx = i - 1 - j;
                    if (idx >= 16) s += hh[15 - j] * vv[idx - 16];
                }
                o[c] = s;
            }
        }
        *(float4*)(yr + o0) = make_float4(o[0], o[1], o[2], o[3]);
    }
}

extern "C" void kernel_launch(void* const* d_in, const int* in_sizes, int n_in,
                              void* d_out, int out_size, void* d_ws, size_t ws_size,
                              hipStream_t stream) {
    const float* x = (const float*)d_in[0];   // (256, 131072) fp32
    const float* h = (const float*)d_in[1];   // (1, 16) fp32
    float* y = (float*)d_out;                 // (256, 131072) fp32
    float* g = (float*)d_ws;                  // 33 floats of scratch

    compute_g_kernel<<<1, 64, 0, stream>>>(h, g);
    fir2_kernel<<<32768, 256, 0, stream>>>(x, h, g, y);
}